// Round 2
// baseline (487.090 us; speedup 1.0000x reference)
//
#include <hip/hip_runtime.h>
#include <hip/hip_bf16.h>

#define T_LEN 96
#define C_CH  66
#define FIN   7128   // 9*66*12
#define KPAD  7168   // 224*32
#define NFC1  1936
#define NPAD  2048
#define NCLS  14

typedef __bf16 bf16x8 __attribute__((ext_vector_type(8)));
typedef float  f32x4  __attribute__((ext_vector_type(4)));

#define GLD_LDS(gp, lp) __builtin_amdgcn_global_load_lds(                     \
    (__attribute__((address_space(1))) void*)(gp),                            \
    (__attribute__((address_space(3))) void*)(lp), 16, 0, 0)

// ---------------------------------------------------------------------------
// Kernel 0: transpose x (B, T*C) -> xT (T*C, B) so conv lanes (lane=b) read
// coalesced. 64x64 LDS tile, +1 pad.
__global__ __launch_bounds__(256) void transpose_kernel(
    const float* __restrict__ x, float* __restrict__ xT, int B)
{
    __shared__ float tile[64][65];
    const int t = threadIdx.x & 63;
    const int w = threadIdx.x >> 6;
    const int tc0 = blockIdx.x * 64;     // 6336 / 64 = 99
    const int b0  = blockIdx.y * 64;     // B / 64
    #pragma unroll
    for (int j = 0; j < 16; j++) {
        const int r = w * 16 + j;
        tile[r][t] = x[(size_t)(b0 + r) * (T_LEN * C_CH) + tc0 + t];
    }
    __syncthreads();
    #pragma unroll
    for (int j = 0; j < 16; j++) {
        const int r = w * 16 + j;
        xT[(size_t)(tc0 + r) * B + b0 + t] = tile[t][r];
    }
}

// ---------------------------------------------------------------------------
// Kernel 1: w_fc1 (1936 x 7128 fp32) -> bf16 (2048 x 7168), zero padded.
__global__ __launch_bounds__(256) void pad_w_kernel(
    const float* __restrict__ w, __hip_bfloat16* __restrict__ wb)
{
    int idx = blockIdx.x * 256 + threadIdx.x;     // chunk id, total 2048*896
    int row = idx / 896;
    int cc  = idx - row * 896;                    // 896 chunks of 8 per row
    float4 a = {0.f, 0.f, 0.f, 0.f}, b = {0.f, 0.f, 0.f, 0.f};
    if (row < NFC1 && cc < 891) {                 // 891*8 = 7128
        const float4* src = (const float4*)(w + (size_t)row * FIN + cc * 8);
        a = src[0];
        b = src[1];
    }
    __align__(16) __hip_bfloat16 v[8];
    v[0] = __float2bfloat16(a.x); v[1] = __float2bfloat16(a.y);
    v[2] = __float2bfloat16(a.z); v[3] = __float2bfloat16(a.w);
    v[4] = __float2bfloat16(b.x); v[5] = __float2bfloat16(b.y);
    v[6] = __float2bfloat16(b.z); v[7] = __float2bfloat16(b.w);
    *(int4*)(wb + (size_t)row * KPAD + cc * 8) = *(const int4*)v;
}

// ---------------------------------------------------------------------------
// Kernel 2: conv branches, per-lane pipeline. REGISTER-BUDGETED RETILE:
// 8 tiles x 6 stage-2 pre-pool positions; stage-2 pooled output lives in a
// mod-12 ring rg[4][12] (static indices, tile loop fully unrolled); stage-3
// outputs are emitted ASAP, as soon as their ring window is complete.
// Peak live set ~116 floats (K=7) / ~84 (K=3) -> fits 128 VGPRs, no spill
// (the 4x12-tile version kept ~200 live -> spilled: WRITE_SIZE 62.7MB vs
// 29.4MB of real output).
// BUGFIX vs failed r1: x-window origin is X0 = 12*tt - 3*PAD (stage-1 tap
// global index = 2p+k-PAD with p = 6tt-PAD+j  =>  12tt - 3PAD + 2j + k).
// The failed version used 2*PAD (shifted all taps). With the corrected X0
// the orig pool2^3 windows no longer each fit in an 18-wide K=3 tile, so
// the low branch's x window is widened to 20 (coverage: a multiple of 12
// exists in [8r+11-XW, 8r+3] iff XW >= 20; each r covered, dups harmless).
// One lane = one (b, c); 256-thread blocks (wave = b-subgroup);
// grid (2, C, B/256): x=0 high (K=7), x=1 low (K=3), branch fastest-varying.
template <int K, bool DO_EXTRA>
__device__ __forceinline__ void conv_branch(
    const float* __restrict__ xb, int ts,
    const float* __restrict__ wS, const float* __restrict__ bS,
    const float* __restrict__ wi1, const float* __restrict__ bi1,
    const float* __restrict__ wi2, const float* __restrict__ bi2,
    __hip_bfloat16* __restrict__ frow, int out_off)
{
    constexpr int PAD = K / 2;
    constexpr int THW = 6 + 2 * PAD;        // stage-1 pooled window per tile
    constexpr int XW  = 12 + 6 * PAD;       // conv x window per tile (30/18)
    constexpr int XWL = DO_EXTRA ? (XW + 2) : XW;   // +2 for orig coverage

    float rg[4][12];                        // stage-2 pooled ring (mod 12)

    #pragma unroll
    for (int tt = 0; tt < 8; tt++) {        // fully unrolled: indices const
        const int X0 = 12 * tt - 3 * PAD;
        // x window: global t = X0 + i (zero outside [0,96))
        float xw[XWL];
        #pragma unroll
        for (int i = 0; i < XWL; i++) {
            const int t = X0 + i;           // compile-time
            xw[i] = (t >= 0 && t < T_LEN) ? xb[(size_t)t * ts] : 0.f;
        }

        if (DO_EXTRA) {
            // orig = pool2^3: emit window [8r, 8r+8) wherever fully covered
            // (each r covered at least once; duplicates write same value).
            #pragma unroll
            for (int r = 0; r < 12; r++) {
                const int lo = 8 * r - X0;  // compile-time
                if (lo >= 0 && lo + 8 <= XWL) {
                    float s = 0.f;
                    #pragma unroll
                    for (int k = 0; k < 8; k++) s += xw[lo + k];
                    frow[r] = __float2bfloat16(s * 0.125f);
                }
            }
        }

        float s2a[4][6];
        #pragma unroll
        for (int oc = 0; oc < 4; oc++) {
            const float bv = bi1[oc];
            #pragma unroll
            for (int q = 0; q < 6; q++) s2a[oc][q] = bv;
        }

        #pragma unroll 1
        for (int ic = 0; ic < 8; ic++) {
            const float bs1 = bS[ic];
            float thw[THW];                 // stage-1 pooled window (this ic)
            #pragma unroll
            for (int j = 0; j < THW; j++) {
                const int p = 6 * tt - PAD + j;      // compile-time
                if (p < 0 || p >= 48) { thw[j] = 0.f; continue; }
                float y0 = bs1, y1 = bs1;
                #pragma unroll
                for (int k = 0; k < K; k++) {
                    const float w = wS[ic * K + k];
                    y0 = fmaf(w, xw[2 * j + k], y0);
                    y1 = fmaf(w, xw[2 * j + 1 + k], y1);
                }
                thw[j] = 0.5f * (fmaxf(y0, 0.f) + fmaxf(y1, 0.f));
            }
            #pragma unroll
            for (int q = 0; q < 6; q++) {
                #pragma unroll
                for (int oc = 0; oc < 4; oc++) {
                    float a = s2a[oc][q];
                    #pragma unroll
                    for (int k = 0; k < K; k++)
                        a = fmaf(wi1[(oc * 8 + ic) * K + k], thw[q + k], a);
                    s2a[oc][q] = a;
                }
            }
        }

        // pool stage 2 -> ring slot (3*tt + r) % 12
        #pragma unroll
        for (int oc = 0; oc < 4; oc++)
            #pragma unroll
            for (int r = 0; r < 3; r++)
                rg[oc][(3 * tt + r) % 12] =
                    0.5f * (fmaxf(s2a[oc][2 * r], 0.f) +
                            fmaxf(s2a[oc][2 * r + 1], 0.f));

        // stage-3 + relu + pool2, emitted ASAP. Output q needs ring indices
        // [2q-PAD, 2q+PAD+1]; after tile tt the ring holds [3tt-9, 3tt+2].
        // Emit when newly ready (tail forced at tt==7); ring-validity of the
        // min index verified statically for both K.
        #pragma unroll
        for (int q = 0; q < 12; q++) {
            const bool now    = (2 * q + PAD + 1 <= 3 * tt + 2) || (tt == 7);
            const bool before = (tt > 0) && (2 * q + PAD + 1 <= 3 * tt - 1);
            if (now && !before) {
                #pragma unroll
                for (int oc = 0; oc < 4; oc++) {
                    float y0 = bi2[oc], y1 = bi2[oc];
                    #pragma unroll
                    for (int ic = 0; ic < 4; ic++) {
                        #pragma unroll
                        for (int k = 0; k < K; k++) {
                            const float w = wi2[(oc * 4 + ic) * K + k];
                            const int i0 = 2 * q + k - PAD;   // compile-time
                            const int i1 = i0 + 1;
                            if (i0 >= 0 && i0 < 24)
                                y0 = fmaf(w, rg[ic][i0 % 12], y0);
                            if (i1 >= 0 && i1 < 24)
                                y1 = fmaf(w, rg[ic][i1 % 12], y1);
                        }
                    }
                    frow[out_off + oc * 12 + q] =
                        __float2bfloat16(0.5f * (fmaxf(y0, 0.f) +
                                                 fmaxf(y1, 0.f)));
                }
            }
        }
    }
}

__global__ __launch_bounds__(256, 3) void conv_fused_kernel(
    const float* __restrict__ x, int ts, int bs, int cs,
    const float* __restrict__ w_hs, const float* __restrict__ b_hs,
    const float* __restrict__ w_ls, const float* __restrict__ b_ls,
    const float* __restrict__ w_hi1, const float* __restrict__ b_hi1,
    const float* __restrict__ w_hi2, const float* __restrict__ b_hi2,
    const float* __restrict__ w_li1, const float* __restrict__ b_li1,
    const float* __restrict__ w_li2, const float* __restrict__ b_li2,
    __hip_bfloat16* __restrict__ feat)
{
    const int lane = threadIdx.x & 63;
    const int wsub = threadIdx.x >> 6;
    const int b = blockIdx.z * 256 + wsub * 64 + lane;
    const int c = blockIdx.y;
    const float* xb = x + (size_t)b * bs + (size_t)c * cs;
    __hip_bfloat16* frow = feat + (size_t)b * KPAD + c * 108;

    if (blockIdx.x == 0) {
        conv_branch<7, false>(xb, ts, w_hs, b_hs,
                              w_hi1 + c * 224, b_hi1 + c * 4,
                              w_hi2 + c * 112, b_hi2 + c * 4, frow, 60);
    } else {
        if (c == 0) {                   // zero K-pad tail once per row
            int4* tail = (int4*)(feat + (size_t)b * KPAD + FIN);
            const int4 z = {0, 0, 0, 0};
            #pragma unroll
            for (int i = 0; i < 5; i++) tail[i] = z;
        }
        conv_branch<3, true>(xb, ts, w_ls, b_ls,
                             w_li1 + c * 96, b_li1 + c * 4,
                             w_li2 + c * 48, b_li2 + c * 4, frow, 12);
    }
}

// ---------------------------------------------------------------------------
// Kernel 3: FC1 GEMM, A(2048xKPAD bf16) * W(2048xKPAD bf16)^T, split-K,
// plain fp32 stores into slabs (no atomics); bias/relu/reduce in fc2.
__global__ __launch_bounds__(256) void gemm_kernel(
    const __hip_bfloat16* __restrict__ A,
    const __hip_bfloat16* __restrict__ Bw,
    float* __restrict__ Cm, int kchunk)
{
    __shared__ __align__(16) __hip_bfloat16 As[4096];  // 128 x 32
    __shared__ __align__(16) __hip_bfloat16 Bs[4096];  // 128 x 32

    const int tid  = threadIdx.x;
    const int lane = tid & 63;
    const int wid  = tid >> 6;
    const int m0 = blockIdx.y * 128;
    const int n0 = blockIdx.x * 128;
    const int wm = (wid >> 1) * 64;
    const int wn = (wid & 1) * 64;
    const int lr = lane & 15;
    const int quad = lane >> 4;

    const int r0 = tid >> 2, c0 = (tid & 3) * 8;
    const __hip_bfloat16* gA0 = A  + (size_t)(m0 + r0) * KPAD + c0;
    const __hip_bfloat16* gA1 = gA0 + (size_t)64 * KPAD;
    const __hip_bfloat16* gB0 = Bw + (size_t)(n0 + r0) * KPAD + c0;
    const __hip_bfloat16* gB1 = gB0 + (size_t)64 * KPAD;
    __hip_bfloat16* lA0 = As + wid * 512;
    __hip_bfloat16* lA1 = As + 2048 + wid * 512;
    __hip_bfloat16* lB0 = Bs + wid * 512;
    __hip_bfloat16* lB1 = Bs + 2048 + wid * 512;

    f32x4 acc[4][4] = {};

    const int kBeg = blockIdx.z * kchunk;
    const int kEnd = kBeg + kchunk;
    for (int k0 = kBeg; k0 < kEnd; k0 += 32) {
        __syncthreads();
        GLD_LDS(gA0 + k0, lA0);
        GLD_LDS(gA1 + k0, lA1);
        GLD_LDS(gB0 + k0, lB0);
        GLD_LDS(gB1 + k0, lB1);
        __syncthreads();
        bf16x8 af[4], bfr[4];
        #pragma unroll
        for (int mt = 0; mt < 4; mt++)
            af[mt] = *(const bf16x8*)(As + (wm + mt * 16 + lr) * 32 + quad * 8);
        #pragma unroll
        for (int nt = 0; nt < 4; nt++)
            bfr[nt] = *(const bf16x8*)(Bs + (wn + nt * 16 + lr) * 32 + quad * 8);
        #pragma unroll
        for (int mt = 0; mt < 4; mt++)
            #pragma unroll
            for (int nt = 0; nt < 4; nt++)
                acc[mt][nt] = __builtin_amdgcn_mfma_f32_16x16x32_bf16(
                    af[mt], bfr[nt], acc[mt][nt], 0, 0, 0);
    }

    // epilogue: C/D layout col = lane&15, row = quad*4 + reg
    float* Cs = Cm + (size_t)blockIdx.z * NPAD * NPAD;
    #pragma unroll
    for (int mt = 0; mt < 4; mt++) {
        #pragma unroll
        for (int nt = 0; nt < 4; nt++) {
            const int col = n0 + wn + nt * 16 + lr;
            const int rb  = m0 + wm + mt * 16 + quad * 4;
            #pragma unroll
            for (int r = 0; r < 4; r++)
                Cs[(size_t)(rb + r) * NPAD + col] = acc[mt][nt][r];
        }
    }
}

// ---------------------------------------------------------------------------
// Kernel 4: reduce split-K slabs + bias + relu, then FC2. One block per row.
__global__ __launch_bounds__(256) void fc2_kernel(
    const float* __restrict__ h1, const float* __restrict__ b1,
    const float* __restrict__ w2, const float* __restrict__ b2,
    float* __restrict__ out, int nslab)
{
    const int b = blockIdx.x;
    const int tid = threadIdx.x;
    float acc[NCLS];
    #pragma unroll
    for (int o = 0; o < NCLS; o++) acc[o] = 0.f;
    for (int n = tid; n < NFC1; n += 256) {
        float hv = b1[n];
        for (int s = 0; s < nslab; s++)
            hv += h1[(size_t)s * NPAD * NPAD + (size_t)b * NPAD + n];
        float h = fmaxf(hv, 0.f);
        #pragma unroll
        for (int o = 0; o < NCLS; o++)
            acc[o] = fmaf(h, w2[o * NFC1 + n], acc[o]);
    }
    __shared__ float red[4][NCLS];
    #pragma unroll
    for (int o = 0; o < NCLS; o++) {
        float v = acc[o];
        #pragma unroll
        for (int s = 32; s > 0; s >>= 1) v += __shfl_down(v, s);
        if ((tid & 63) == 0) red[tid >> 6][o] = v;
    }
    __syncthreads();
    if (tid < NCLS)
        out[b * NCLS + tid] = red[0][tid] + red[1][tid] + red[2][tid] +
                              red[3][tid] + b2[tid];
}

// ---------------------------------------------------------------------------
extern "C" void kernel_launch(void* const* d_in, const int* in_sizes, int n_in,
                              void* d_out, int out_size, void* d_ws, size_t ws_size,
                              hipStream_t stream)
{
    (void)n_in; (void)out_size;
    const float* x     = (const float*)d_in[0];
    const float* w_hs  = (const float*)d_in[1];
    const float* b_hs  = (const float*)d_in[2];
    const float* w_ls  = (const float*)d_in[3];
    const float* b_ls  = (const float*)d_in[4];
    const float* w_hi1 = (const float*)d_in[5];
    const float* b_hi1 = (const float*)d_in[6];
    const float* w_hi2 = (const float*)d_in[7];
    const float* b_hi2 = (const float*)d_in[8];
    const float* w_li1 = (const float*)d_in[9];
    const float* b_li1 = (const float*)d_in[10];
    const float* w_li2 = (const float*)d_in[11];
    const float* b_li2 = (const float*)d_in[12];
    const float* w_fc1 = (const float*)d_in[13];
    const float* b_fc1 = (const float*)d_in[14];
    const float* w_fc2 = (const float*)d_in[15];
    const float* b_fc2 = (const float*)d_in[16];
    float* out = (float*)d_out;

    const int B = in_sizes[0] / (T_LEN * C_CH);    // 2048

    char* ws = (char*)d_ws;
    const size_t featB = (size_t)B * KPAD * 2;         // 29.4 MB
    const size_t wbB   = (size_t)NPAD * KPAD * 2;      // 29.4 MB
    const size_t slabB = (size_t)NPAD * NPAD * 4;      // 16.8 MB
    const size_t xtB   = (size_t)T_LEN * C_CH * B * 4; // 51.9 MB
    const size_t base2 = featB + wbB;

    __hip_bfloat16* feat = (__hip_bfloat16*)ws;
    __hip_bfloat16* wb   = (__hip_bfloat16*)(ws + featB);
    float* h1            = (float*)(ws + base2);

    const int sk = (ws_size >= base2 + 4 * slabB) ? 4 : 2;
    const bool use_xt = (ws_size >= base2 + sk * slabB + xtB);
    float* xT = (float*)(ws + base2 + sk * slabB);

    pad_w_kernel<<<dim3((NPAD * 896) / 256), 256, 0, stream>>>(w_fc1, wb);

    const float* cx = x;
    int ts = C_CH, bsi = T_LEN * C_CH, cs = 1;
    if (use_xt) {
        transpose_kernel<<<dim3(99, B / 64), 256, 0, stream>>>(x, xT, B);
        cx = xT; ts = C_CH * B; bsi = 1; cs = B;
    }
    conv_fused_kernel<<<dim3(2, C_CH, B / 256), 256, 0, stream>>>(
        cx, ts, bsi, cs, w_hs, b_hs, w_ls, b_ls,
        w_hi1, b_hi1, w_hi2, b_hi2, w_li1, b_li1, w_li2, b_li2, feat);
    gemm_kernel<<<dim3(NPAD / 128, B / 128, sk), 256, 0, stream>>>(
        feat, wb, h1, KPAD / sk);
    fc2_kernel<<<dim3(B), 256, 0, stream>>>(h1, b_fc1, w_fc2, b_fc2, out, sk);
}

// Round 3
// 482.866 us; speedup vs baseline: 1.0087x; 1.0087x over previous
//
#include <hip/hip_runtime.h>
#include <hip/hip_bf16.h>

#define T_LEN 96
#define C_CH  66
#define FIN   7128   // 9*66*12
#define KPAD  7168   // 224*32
#define NFC1  1936
#define NPAD  2048
#define NCLS  14

typedef __bf16 bf16x8 __attribute__((ext_vector_type(8)));
typedef float  f32x4  __attribute__((ext_vector_type(4)));

#define GLD_LDS(gp, lp) __builtin_amdgcn_global_load_lds(                     \
    (__attribute__((address_space(1))) void*)(gp),                            \
    (__attribute__((address_space(3))) void*)(lp), 16, 0, 0)

// ---------------------------------------------------------------------------
// Kernel 0: transpose x (B, T*C) -> xT (T*C, B) so conv lanes (lane=b) read
// coalesced. 64x64 LDS tile, +1 pad.
__global__ __launch_bounds__(256) void transpose_kernel(
    const float* __restrict__ x, float* __restrict__ xT, int B)
{
    __shared__ float tile[64][65];
    const int t = threadIdx.x & 63;
    const int w = threadIdx.x >> 6;
    const int tc0 = blockIdx.x * 64;     // 6336 / 64 = 99
    const int b0  = blockIdx.y * 64;     // B / 64
    #pragma unroll
    for (int j = 0; j < 16; j++) {
        const int r = w * 16 + j;
        tile[r][t] = x[(size_t)(b0 + r) * (T_LEN * C_CH) + tc0 + t];
    }
    __syncthreads();
    #pragma unroll
    for (int j = 0; j < 16; j++) {
        const int r = w * 16 + j;
        xT[(size_t)(tc0 + r) * B + b0 + t] = tile[t][r];
    }
}

// ---------------------------------------------------------------------------
// Kernel 1: w_fc1 (1936 x 7128 fp32) -> bf16 (2048 x 7168), zero padded.
__global__ __launch_bounds__(256) void pad_w_kernel(
    const float* __restrict__ w, __hip_bfloat16* __restrict__ wb)
{
    int idx = blockIdx.x * 256 + threadIdx.x;     // chunk id, total 2048*896
    int row = idx / 896;
    int cc  = idx - row * 896;                    // 896 chunks of 8 per row
    float4 a = {0.f, 0.f, 0.f, 0.f}, b = {0.f, 0.f, 0.f, 0.f};
    if (row < NFC1 && cc < 891) {                 // 891*8 = 7128
        const float4* src = (const float4*)(w + (size_t)row * FIN + cc * 8);
        a = src[0];
        b = src[1];
    }
    __align__(16) __hip_bfloat16 v[8];
    v[0] = __float2bfloat16(a.x); v[1] = __float2bfloat16(a.y);
    v[2] = __float2bfloat16(a.z); v[3] = __float2bfloat16(a.w);
    v[4] = __float2bfloat16(b.x); v[5] = __float2bfloat16(b.y);
    v[6] = __float2bfloat16(b.z); v[7] = __float2bfloat16(b.w);
    *(int4*)(wb + (size_t)row * KPAD + cc * 8) = *(const int4*)v;
}

// ---------------------------------------------------------------------------
// Kernel 2: conv branches. 8 tiles x 6 stage-2 pre-pool positions; stage-2
// pooled output lives in a mod-12 ring rg[4][12]; stage-3 outputs emitted
// ASAP once their ring window is complete. Peak live set ~116 floats (K=7).
//
// ROUND-3 FIX: round 2 relied on `#pragma unroll` of the 8-iteration tile
// loop; clang's unroller bailed (huge body + inner rolled loop), leaving tt
// runtime -> every ring/window index became runtime -> ALL arrays demoted to
// scratch (VGPR_Count=40, WRITE_SIZE 317MB vs 29.4MB real, conv 240us).
// Tiles are now expanded STRUCTURALLY: conv_tile<K,DO_EXTRA,TT> called for
// TT=0..7, so all indices are compile-time constants by construction and
// register promotion cannot be defeated by unroll heuristics.
template <int K, bool DO_EXTRA, int TT>
__device__ __forceinline__ void conv_tile(
    const float* __restrict__ xb, int ts,
    const float* __restrict__ wS, const float* __restrict__ bS,
    const float* __restrict__ wi1, const float* __restrict__ bi1,
    const float* __restrict__ wi2, const float* __restrict__ bi2,
    __hip_bfloat16* __restrict__ frow, int out_off,
    float (&rg)[4][12])
{
    constexpr int PAD = K / 2;
    constexpr int THW = 6 + 2 * PAD;        // stage-1 pooled window per tile
    constexpr int XW  = 12 + 6 * PAD;       // conv x window per tile (30/18)
    constexpr int XWL = DO_EXTRA ? (XW + 2) : XW;   // +2 for orig coverage
    constexpr int X0  = 12 * TT - 3 * PAD;  // stage-1 tap t = 12TT-3PAD+2j+k

    // x window: global t = X0 + i (zero outside [0,96))
    float xw[XWL];
    #pragma unroll
    for (int i = 0; i < XWL; i++) {
        const int t = X0 + i;               // compile-time
        xw[i] = (t >= 0 && t < T_LEN) ? xb[(size_t)t * ts] : 0.f;
    }

    if constexpr (DO_EXTRA) {
        // orig = pool2^3: emit window [8r, 8r+8) wherever fully covered
        // (each r covered at least once; duplicates write same value).
        #pragma unroll
        for (int r = 0; r < 12; r++) {
            const int lo = 8 * r - X0;      // compile-time
            if (lo >= 0 && lo + 8 <= XWL) {
                float s = 0.f;
                #pragma unroll
                for (int k = 0; k < 8; k++) s += xw[lo + k];
                frow[r] = __float2bfloat16(s * 0.125f);
            }
        }
    }

    float s2a[4][6];
    #pragma unroll
    for (int oc = 0; oc < 4; oc++) {
        const float bv = bi1[oc];
        #pragma unroll
        for (int q = 0; q < 6; q++) s2a[oc][q] = bv;
    }

    #pragma unroll 1
    for (int ic = 0; ic < 8; ic++) {
        const float bs1 = bS[ic];
        float thw[THW];                     // stage-1 pooled window (this ic)
        #pragma unroll
        for (int j = 0; j < THW; j++) {
            const int p = 6 * TT - PAD + j;          // compile-time
            if (p < 0 || p >= 48) { thw[j] = 0.f; continue; }
            float y0 = bs1, y1 = bs1;
            #pragma unroll
            for (int k = 0; k < K; k++) {
                const float w = wS[ic * K + k];
                y0 = fmaf(w, xw[2 * j + k], y0);
                y1 = fmaf(w, xw[2 * j + 1 + k], y1);
            }
            thw[j] = 0.5f * (fmaxf(y0, 0.f) + fmaxf(y1, 0.f));
        }
        #pragma unroll
        for (int q = 0; q < 6; q++) {
            #pragma unroll
            for (int oc = 0; oc < 4; oc++) {
                float a = s2a[oc][q];
                #pragma unroll
                for (int k = 0; k < K; k++)
                    a = fmaf(wi1[(oc * 8 + ic) * K + k], thw[q + k], a);
                s2a[oc][q] = a;
            }
        }
    }

    // pool stage 2 -> ring slot (3*TT + r) % 12 (compile-time)
    #pragma unroll
    for (int oc = 0; oc < 4; oc++)
        #pragma unroll
        for (int r = 0; r < 3; r++)
            rg[oc][(3 * TT + r) % 12] =
                0.5f * (fmaxf(s2a[oc][2 * r], 0.f) +
                        fmaxf(s2a[oc][2 * r + 1], 0.f));

    // stage-3 + relu + pool2, emitted ASAP. Output q needs ring indices
    // [2q-PAD, 2q+PAD+1]; after tile TT the ring holds [3TT-9, 3TT+2].
    // Emit when newly ready (tail forced at TT==7).
    #pragma unroll
    for (int q = 0; q < 12; q++) {
        const bool now    = (2 * q + PAD + 1 <= 3 * TT + 2) || (TT == 7);
        const bool before = (TT > 0) && (2 * q + PAD + 1 <= 3 * TT - 1);
        if (now && !before) {
            #pragma unroll
            for (int oc = 0; oc < 4; oc++) {
                float y0 = bi2[oc], y1 = bi2[oc];
                #pragma unroll
                for (int ic = 0; ic < 4; ic++) {
                    #pragma unroll
                    for (int k = 0; k < K; k++) {
                        const float w = wi2[(oc * 4 + ic) * K + k];
                        const int i0 = 2 * q + k - PAD;   // compile-time
                        const int i1 = i0 + 1;
                        if (i0 >= 0 && i0 < 24)
                            y0 = fmaf(w, rg[ic][i0 % 12], y0);
                        if (i1 >= 0 && i1 < 24)
                            y1 = fmaf(w, rg[ic][i1 % 12], y1);
                    }
                }
                frow[out_off + oc * 12 + q] =
                    __float2bfloat16(0.5f * (fmaxf(y0, 0.f) +
                                             fmaxf(y1, 0.f)));
            }
        }
    }
}

template <int K, bool DO_EXTRA>
__device__ __forceinline__ void conv_branch(
    const float* __restrict__ xb, int ts,
    const float* __restrict__ wS, const float* __restrict__ bS,
    const float* __restrict__ wi1, const float* __restrict__ bi1,
    const float* __restrict__ wi2, const float* __restrict__ bi2,
    __hip_bfloat16* __restrict__ frow, int out_off)
{
    float rg[4][12];                        // stage-2 pooled ring (mod 12)
    conv_tile<K, DO_EXTRA, 0>(xb, ts, wS, bS, wi1, bi1, wi2, bi2, frow, out_off, rg);
    conv_tile<K, DO_EXTRA, 1>(xb, ts, wS, bS, wi1, bi1, wi2, bi2, frow, out_off, rg);
    conv_tile<K, DO_EXTRA, 2>(xb, ts, wS, bS, wi1, bi1, wi2, bi2, frow, out_off, rg);
    conv_tile<K, DO_EXTRA, 3>(xb, ts, wS, bS, wi1, bi1, wi2, bi2, frow, out_off, rg);
    conv_tile<K, DO_EXTRA, 4>(xb, ts, wS, bS, wi1, bi1, wi2, bi2, frow, out_off, rg);
    conv_tile<K, DO_EXTRA, 5>(xb, ts, wS, bS, wi1, bi1, wi2, bi2, frow, out_off, rg);
    conv_tile<K, DO_EXTRA, 6>(xb, ts, wS, bS, wi1, bi1, wi2, bi2, frow, out_off, rg);
    conv_tile<K, DO_EXTRA, 7>(xb, ts, wS, bS, wi1, bi1, wi2, bi2, frow, out_off, rg);
}

__global__ __launch_bounds__(256, 2) void conv_fused_kernel(
    const float* __restrict__ x, int ts, int bs, int cs,
    const float* __restrict__ w_hs, const float* __restrict__ b_hs,
    const float* __restrict__ w_ls, const float* __restrict__ b_ls,
    const float* __restrict__ w_hi1, const float* __restrict__ b_hi1,
    const float* __restrict__ w_hi2, const float* __restrict__ b_hi2,
    const float* __restrict__ w_li1, const float* __restrict__ b_li1,
    const float* __restrict__ w_li2, const float* __restrict__ b_li2,
    __hip_bfloat16* __restrict__ feat)
{
    const int lane = threadIdx.x & 63;
    const int wsub = threadIdx.x >> 6;
    const int b = blockIdx.z * 256 + wsub * 64 + lane;
    const int c = blockIdx.y;
    const float* xb = x + (size_t)b * bs + (size_t)c * cs;
    __hip_bfloat16* frow = feat + (size_t)b * KPAD + c * 108;

    if (blockIdx.x == 0) {
        conv_branch<7, false>(xb, ts, w_hs, b_hs,
                              w_hi1 + c * 224, b_hi1 + c * 4,
                              w_hi2 + c * 112, b_hi2 + c * 4, frow, 60);
    } else {
        if (c == 0) {                   // zero K-pad tail once per row
            int4* tail = (int4*)(feat + (size_t)b * KPAD + FIN);
            const int4 z = {0, 0, 0, 0};
            #pragma unroll
            for (int i = 0; i < 5; i++) tail[i] = z;
        }
        conv_branch<3, true>(xb, ts, w_ls, b_ls,
                             w_li1 + c * 96, b_li1 + c * 4,
                             w_li2 + c * 48, b_li2 + c * 4, frow, 12);
    }
}

// ---------------------------------------------------------------------------
// Kernel 3: FC1 GEMM, A(2048xKPAD bf16) * W(2048xKPAD bf16)^T, split-K,
// plain fp32 stores into slabs (no atomics); bias/relu/reduce in fc2.
__global__ __launch_bounds__(256) void gemm_kernel(
    const __hip_bfloat16* __restrict__ A,
    const __hip_bfloat16* __restrict__ Bw,
    float* __restrict__ Cm, int kchunk)
{
    __shared__ __align__(16) __hip_bfloat16 As[4096];  // 128 x 32
    __shared__ __align__(16) __hip_bfloat16 Bs[4096];  // 128 x 32

    const int tid  = threadIdx.x;
    const int lane = tid & 63;
    const int wid  = tid >> 6;
    const int m0 = blockIdx.y * 128;
    const int n0 = blockIdx.x * 128;
    const int wm = (wid >> 1) * 64;
    const int wn = (wid & 1) * 64;
    const int lr = lane & 15;
    const int quad = lane >> 4;

    const int r0 = tid >> 2, c0 = (tid & 3) * 8;
    const __hip_bfloat16* gA0 = A  + (size_t)(m0 + r0) * KPAD + c0;
    const __hip_bfloat16* gA1 = gA0 + (size_t)64 * KPAD;
    const __hip_bfloat16* gB0 = Bw + (size_t)(n0 + r0) * KPAD + c0;
    const __hip_bfloat16* gB1 = gB0 + (size_t)64 * KPAD;
    __hip_bfloat16* lA0 = As + wid * 512;
    __hip_bfloat16* lA1 = As + 2048 + wid * 512;
    __hip_bfloat16* lB0 = Bs + wid * 512;
    __hip_bfloat16* lB1 = Bs + 2048 + wid * 512;

    f32x4 acc[4][4] = {};

    const int kBeg = blockIdx.z * kchunk;
    const int kEnd = kBeg + kchunk;
    for (int k0 = kBeg; k0 < kEnd; k0 += 32) {
        __syncthreads();
        GLD_LDS(gA0 + k0, lA0);
        GLD_LDS(gA1 + k0, lA1);
        GLD_LDS(gB0 + k0, lB0);
        GLD_LDS(gB1 + k0, lB1);
        __syncthreads();
        bf16x8 af[4], bfr[4];
        #pragma unroll
        for (int mt = 0; mt < 4; mt++)
            af[mt] = *(const bf16x8*)(As + (wm + mt * 16 + lr) * 32 + quad * 8);
        #pragma unroll
        for (int nt = 0; nt < 4; nt++)
            bfr[nt] = *(const bf16x8*)(Bs + (wn + nt * 16 + lr) * 32 + quad * 8);
        #pragma unroll
        for (int mt = 0; mt < 4; mt++)
            #pragma unroll
            for (int nt = 0; nt < 4; nt++)
                acc[mt][nt] = __builtin_amdgcn_mfma_f32_16x16x32_bf16(
                    af[mt], bfr[nt], acc[mt][nt], 0, 0, 0);
    }

    // epilogue: C/D layout col = lane&15, row = quad*4 + reg
    float* Cs = Cm + (size_t)blockIdx.z * NPAD * NPAD;
    #pragma unroll
    for (int mt = 0; mt < 4; mt++) {
        #pragma unroll
        for (int nt = 0; nt < 4; nt++) {
            const int col = n0 + wn + nt * 16 + lr;
            const int rb  = m0 + wm + mt * 16 + quad * 4;
            #pragma unroll
            for (int r = 0; r < 4; r++)
                Cs[(size_t)(rb + r) * NPAD + col] = acc[mt][nt][r];
        }
    }
}

// ---------------------------------------------------------------------------
// Kernel 4: reduce split-K slabs + bias + relu, then FC2. One block per row.
__global__ __launch_bounds__(256) void fc2_kernel(
    const float* __restrict__ h1, const float* __restrict__ b1,
    const float* __restrict__ w2, const float* __restrict__ b2,
    float* __restrict__ out, int nslab)
{
    const int b = blockIdx.x;
    const int tid = threadIdx.x;
    float acc[NCLS];
    #pragma unroll
    for (int o = 0; o < NCLS; o++) acc[o] = 0.f;
    for (int n = tid; n < NFC1; n += 256) {
        float hv = b1[n];
        for (int s = 0; s < nslab; s++)
            hv += h1[(size_t)s * NPAD * NPAD + (size_t)b * NPAD + n];
        float h = fmaxf(hv, 0.f);
        #pragma unroll
        for (int o = 0; o < NCLS; o++)
            acc[o] = fmaf(h, w2[o * NFC1 + n], acc[o]);
    }
    __shared__ float red[4][NCLS];
    #pragma unroll
    for (int o = 0; o < NCLS; o++) {
        float v = acc[o];
        #pragma unroll
        for (int s = 32; s > 0; s >>= 1) v += __shfl_down(v, s);
        if ((tid & 63) == 0) red[tid >> 6][o] = v;
    }
    __syncthreads();
    if (tid < NCLS)
        out[b * NCLS + tid] = red[0][tid] + red[1][tid] + red[2][tid] +
                              red[3][tid] + b2[tid];
}

// ---------------------------------------------------------------------------
extern "C" void kernel_launch(void* const* d_in, const int* in_sizes, int n_in,
                              void* d_out, int out_size, void* d_ws, size_t ws_size,
                              hipStream_t stream)
{
    (void)n_in; (void)out_size;
    const float* x     = (const float*)d_in[0];
    const float* w_hs  = (const float*)d_in[1];
    const float* b_hs  = (const float*)d_in[2];
    const float* w_ls  = (const float*)d_in[3];
    const float* b_ls  = (const float*)d_in[4];
    const float* w_hi1 = (const float*)d_in[5];
    const float* b_hi1 = (const float*)d_in[6];
    const float* w_hi2 = (const float*)d_in[7];
    const float* b_hi2 = (const float*)d_in[8];
    const float* w_li1 = (const float*)d_in[9];
    const float* b_li1 = (const float*)d_in[10];
    const float* w_li2 = (const float*)d_in[11];
    const float* b_li2 = (const float*)d_in[12];
    const float* w_fc1 = (const float*)d_in[13];
    const float* b_fc1 = (const float*)d_in[14];
    const float* w_fc2 = (const float*)d_in[15];
    const float* b_fc2 = (const float*)d_in[16];
    float* out = (float*)d_out;

    const int B = in_sizes[0] / (T_LEN * C_CH);    // 2048

    char* ws = (char*)d_ws;
    const size_t featB = (size_t)B * KPAD * 2;         // 29.4 MB
    const size_t wbB   = (size_t)NPAD * KPAD * 2;      // 29.4 MB
    const size_t slabB = (size_t)NPAD * NPAD * 4;      // 16.8 MB
    const size_t xtB   = (size_t)T_LEN * C_CH * B * 4; // 51.9 MB
    const size_t base2 = featB + wbB;

    __hip_bfloat16* feat = (__hip_bfloat16*)ws;
    __hip_bfloat16* wb   = (__hip_bfloat16*)(ws + featB);
    float* h1            = (float*)(ws + base2);

    const int sk = (ws_size >= base2 + 4 * slabB) ? 4 : 2;
    const bool use_xt = (ws_size >= base2 + sk * slabB + xtB);
    float* xT = (float*)(ws + base2 + sk * slabB);

    pad_w_kernel<<<dim3((NPAD * 896) / 256), 256, 0, stream>>>(w_fc1, wb);

    const float* cx = x;
    int ts = C_CH, bsi = T_LEN * C_CH, cs = 1;
    if (use_xt) {
        transpose_kernel<<<dim3(99, B / 64), 256, 0, stream>>>(x, xT, B);
        cx = xT; ts = C_CH * B; bsi = 1; cs = B;
    }
    conv_fused_kernel<<<dim3(2, C_CH, B / 256), 256, 0, stream>>>(
        cx, ts, bsi, cs, w_hs, b_hs, w_ls, b_ls,
        w_hi1, b_hi1, w_hi2, b_hi2, w_li1, b_li1, w_li2, b_li2, feat);
    gemm_kernel<<<dim3(NPAD / 128, B / 128, sk), 256, 0, stream>>>(
        feat, wb, h1, KPAD / sk);
    fc2_kernel<<<dim3(B), 256, 0, stream>>>(h1, b_fc1, w_fc2, b_fc2, out, sk);
}

// Round 5
// 440.109 us; speedup vs baseline: 1.1067x; 1.0972x over previous
//
#include <hip/hip_runtime.h>
#include <hip/hip_bf16.h>

#define T_LEN 96
#define C_CH  66
#define FIN   7128   // 9*66*12
#define KPAD  7168   // 224*32
#define NFC1  1936
#define NPAD  2048
#define NCLS  14

typedef __bf16 bf16x8 __attribute__((ext_vector_type(8)));
typedef float  f32x4  __attribute__((ext_vector_type(4)));

#define GLD_LDS(gp, lp) __builtin_amdgcn_global_load_lds(                     \
    (__attribute__((address_space(1))) void*)(gp),                            \
    (__attribute__((address_space(3))) void*)(lp), 16, 0, 0)

// ---------------------------------------------------------------------------
// Kernel 0: transpose x (B, T*C) -> xT (T*C, B) so conv lanes (lane=b) read
// coalesced. 64x64 LDS tile, +1 pad.
__global__ __launch_bounds__(256) void transpose_kernel(
    const float* __restrict__ x, float* __restrict__ xT, int B)
{
    __shared__ float tile[64][65];
    const int t = threadIdx.x & 63;
    const int w = threadIdx.x >> 6;
    const int tc0 = blockIdx.x * 64;     // 6336 / 64 = 99
    const int b0  = blockIdx.y * 64;     // B / 64
    #pragma unroll
    for (int j = 0; j < 16; j++) {
        const int r = w * 16 + j;
        tile[r][t] = x[(size_t)(b0 + r) * (T_LEN * C_CH) + tc0 + t];
    }
    __syncthreads();
    #pragma unroll
    for (int j = 0; j < 16; j++) {
        const int r = w * 16 + j;
        xT[(size_t)(tc0 + r) * B + b0 + t] = tile[t][r];
    }
}

// ---------------------------------------------------------------------------
// Kernel 1: w_fc1 (1936 x 7128 fp32) -> bf16 (2048 x 7168), zero padded.
__global__ __launch_bounds__(256) void pad_w_kernel(
    const float* __restrict__ w, __hip_bfloat16* __restrict__ wb)
{
    int idx = blockIdx.x * 256 + threadIdx.x;     // chunk id, total 2048*896
    int row = idx / 896;
    int cc  = idx - row * 896;                    // 896 chunks of 8 per row
    float4 a = {0.f, 0.f, 0.f, 0.f}, b = {0.f, 0.f, 0.f, 0.f};
    if (row < NFC1 && cc < 891) {                 // 891*8 = 7128
        const float4* src = (const float4*)(w + (size_t)row * FIN + cc * 8);
        a = src[0];
        b = src[1];
    }
    __align__(16) __hip_bfloat16 v[8];
    v[0] = __float2bfloat16(a.x); v[1] = __float2bfloat16(a.y);
    v[2] = __float2bfloat16(a.z); v[3] = __float2bfloat16(a.w);
    v[4] = __float2bfloat16(b.x); v[5] = __float2bfloat16(b.y);
    v[6] = __float2bfloat16(b.z); v[7] = __float2bfloat16(b.w);
    *(int4*)(wb + (size_t)row * KPAD + cc * 8) = *(const int4*)v;
}

// ---------------------------------------------------------------------------
// Kernel 2: conv branches — EXACT round-0 version (176us, VGPR=128, known
// good). Two retile attempts (mod-12 ring, 8 tiles) both triggered wholesale
// array demotion to scratch (VGPR 40/68, WRITE_SIZE 214-317MB) and LOST vs
// this structure; reverted. Per-lane pipeline TILED over positions, tile t
// covers stage-2 pre-pool positions [12t, 12t+12); stage-2 pooled output
// accumulates in static-index register array s2phR[4][24].
// One lane = one (b, c); grid (B/64, C, 2): z=0 high (K=7), z=1 low (K=3).
template <int K, bool DO_EXTRA>
__device__ __forceinline__ void conv_branch(
    const float* __restrict__ xb, int ts,
    const float* __restrict__ wS, const float* __restrict__ bS,
    const float* __restrict__ wi1, const float* __restrict__ bi1,
    const float* __restrict__ wi2, const float* __restrict__ bi2,
    __hip_bfloat16* __restrict__ frow, int out_off)
{
    constexpr int PAD = K / 2;
    constexpr int XW  = 24 + 6 * PAD;   // x window per tile
    constexpr int THW = 12 + 2 * PAD;   // stage-1 pooled window per tile

    float s2phR[4][24];                 // stage-2 pooled (static indices)

    #pragma unroll
    for (int tt = 0; tt < 4; tt++) {    // fully unrolled: all indices const
        // x window: global t = 24*tt - 3*PAD + i (zero outside [0,96))
        float xw[XW];
        #pragma unroll
        for (int i = 0; i < XW; i++) {
            const int t = 24 * tt - 3 * PAD + i;     // compile-time
            xw[i] = (t >= 0 && t < T_LEN) ? xb[(size_t)t * ts] : 0.f;
        }

        if (DO_EXTRA) {                 // orig = pool2^3: 3 outputs per tile
            #pragma unroll
            for (int r = 0; r < 3; r++) {
                float s = 0.f;
                #pragma unroll
                for (int k = 0; k < 8; k++) s += xw[3 * PAD + 8 * r + k];
                frow[3 * tt + r] = __float2bfloat16(s * 0.125f);
            }
        }

        float s2a[4][12];
        #pragma unroll
        for (int oc = 0; oc < 4; oc++) {
            const float bv = bi1[oc];
            #pragma unroll
            for (int q = 0; q < 12; q++) s2a[oc][q] = bv;
        }

        #pragma unroll 1
        for (int ic = 0; ic < 8; ic++) {
            const float bs1 = bS[ic];
            float thw[THW];             // stage-1 pooled window (this ic)
            #pragma unroll
            for (int j = 0; j < THW; j++) {
                const int jg = 12 * tt - PAD + j;    // compile-time
                if (jg < 0 || jg >= 48) { thw[j] = 0.f; continue; }
                float y0 = bs1, y1 = bs1;
                #pragma unroll
                for (int k = 0; k < K; k++) {
                    const float w = wS[ic * K + k];
                    y0 = fmaf(w, xw[2 * j + k], y0);
                    y1 = fmaf(w, xw[2 * j + 1 + k], y1);
                }
                thw[j] = 0.5f * (fmaxf(y0, 0.f) + fmaxf(y1, 0.f));
            }
            #pragma unroll
            for (int q = 0; q < 12; q++) {
                #pragma unroll
                for (int oc = 0; oc < 4; oc++) {
                    float a = s2a[oc][q];
                    #pragma unroll
                    for (int k = 0; k < K; k++)
                        a = fmaf(wi1[(oc * 8 + ic) * K + k], thw[q + k], a);
                    s2a[oc][q] = a;
                }
            }
        }

        // pool stage 2 -> s2phR[oc][6*tt + r]
        #pragma unroll
        for (int oc = 0; oc < 4; oc++)
            #pragma unroll
            for (int r = 0; r < 6; r++)
                s2phR[oc][6 * tt + r] =
                    0.5f * (fmaxf(s2a[oc][2 * r], 0.f) +
                            fmaxf(s2a[oc][2 * r + 1], 0.f));
    }

    // stage 3 (grouped 4->4) + relu + pool2; OOB taps statically dropped
    #pragma unroll 1
    for (int oc = 0; oc < 4; oc++) {
        const float bv = bi2[oc];
        #pragma unroll
        for (int q = 0; q < 12; q++) {
            float y0 = bv, y1 = bv;
            #pragma unroll
            for (int ic = 0; ic < 4; ic++) {
                #pragma unroll
                for (int k = 0; k < K; k++) {
                    const float w = wi2[(oc * 4 + ic) * K + k];
                    const int i0 = 2 * q + k - PAD;       // compile-time
                    const int i1 = 2 * q + 1 + k - PAD;
                    if (i0 >= 0 && i0 < 24) y0 = fmaf(w, s2phR[ic][i0], y0);
                    if (i1 >= 0 && i1 < 24) y1 = fmaf(w, s2phR[ic][i1], y1);
                }
            }
            frow[out_off + oc * 12 + q] =
                __float2bfloat16(0.5f * (fmaxf(y0, 0.f) + fmaxf(y1, 0.f)));
        }
    }
}

__global__ __launch_bounds__(64, 2) void conv_fused_kernel(
    const float* __restrict__ x, int ts, int bs, int cs,
    const float* __restrict__ w_hs, const float* __restrict__ b_hs,
    const float* __restrict__ w_ls, const float* __restrict__ b_ls,
    const float* __restrict__ w_hi1, const float* __restrict__ b_hi1,
    const float* __restrict__ w_hi2, const float* __restrict__ b_hi2,
    const float* __restrict__ w_li1, const float* __restrict__ b_li1,
    const float* __restrict__ w_li2, const float* __restrict__ b_li2,
    __hip_bfloat16* __restrict__ feat)
{
    const int lane = threadIdx.x;
    const int b = blockIdx.x * 64 + lane;
    const int c = blockIdx.y;
    const float* xb = x + (size_t)b * bs + (size_t)c * cs;
    __hip_bfloat16* frow = feat + (size_t)b * KPAD + c * 108;

    if (blockIdx.z == 0) {
        conv_branch<7, false>(xb, ts, w_hs, b_hs,
                              w_hi1 + c * 224, b_hi1 + c * 4,
                              w_hi2 + c * 112, b_hi2 + c * 4, frow, 60);
    } else {
        if (c == 0) {                   // zero K-pad tail once per row
            int4* tail = (int4*)(feat + (size_t)b * KPAD + FIN);
            const int4 z = {0, 0, 0, 0};
            #pragma unroll
            for (int i = 0; i < 5; i++) tail[i] = z;
        }
        conv_branch<3, true>(xb, ts, w_ls, b_ls,
                             w_li1 + c * 96, b_li1 + c * 4,
                             w_li2 + c * 48, b_li2 + c * 4, frow, 12);
    }
}

// ---------------------------------------------------------------------------
// Kernel 3: FC1 GEMM, A(2048xKPAD bf16) * W(2048xKPAD bf16)^T, split-K.
// 256x256 tile (was 128x128), 512 threads, 8 waves as 2Mx4N, BK=32.
// Rationale: with 128x128 tiles total panel read traffic was 941MB (L3-BW
// bound -> ~150-190us). 256x256 halves it to 470MB; MFMA:ds_read per K-step
// improves 16:8 -> 32:12. acc[8][4] f32x4 = 128 VGPR, total ~200 < 256 cap.
// Grid (8,8,sk): sk=4 -> 256 blocks = 1/CU, no tail.
__global__ __launch_bounds__(512, 2) void gemm_kernel(
    const __hip_bfloat16* __restrict__ A,
    const __hip_bfloat16* __restrict__ Bw,
    float* __restrict__ Cm, int kchunk)
{
    __shared__ __align__(16) __hip_bfloat16 As[8192];  // 256 x 32
    __shared__ __align__(16) __hip_bfloat16 Bs[8192];  // 256 x 32

    const int tid  = threadIdx.x;
    const int lane = tid & 63;
    const int wid  = tid >> 6;          // 0..7
    const int m0 = blockIdx.y * 256;
    const int n0 = blockIdx.x * 256;
    const int wm = (wid >> 2) * 128;    // 2 wave-rows (128 each)
    const int wn = (wid & 3) * 64;      // 4 wave-cols (64 each)
    const int lr = lane & 15;
    const int quad = lane >> 4;

    // staging: thread tid stages global chunk (row tid>>2, col (tid&3)*8)
    // at LDS elem tid*8; GLD_LDS dest = wave-uniform base wid*512 + lane*16B
    // = (wid*64+lane)*8 = tid*8.  Linear, in-bounds, GLD_LDS-legal.
    const int r0 = tid >> 2, c0 = (tid & 3) * 8;
    const __hip_bfloat16* gA0 = A  + (size_t)(m0 + r0) * KPAD + c0;
    const __hip_bfloat16* gA1 = gA0 + (size_t)128 * KPAD;
    const __hip_bfloat16* gB0 = Bw + (size_t)(n0 + r0) * KPAD + c0;
    const __hip_bfloat16* gB1 = gB0 + (size_t)128 * KPAD;
    __hip_bfloat16* lA0 = As + wid * 512;
    __hip_bfloat16* lA1 = As + 4096 + wid * 512;
    __hip_bfloat16* lB0 = Bs + wid * 512;
    __hip_bfloat16* lB1 = Bs + 4096 + wid * 512;

    f32x4 acc[8][4] = {};

    const int kBeg = blockIdx.z * kchunk;
    const int kEnd = kBeg + kchunk;
    for (int k0 = kBeg; k0 < kEnd; k0 += 32) {
        __syncthreads();
        GLD_LDS(gA0 + k0, lA0);
        GLD_LDS(gA1 + k0, lA1);
        GLD_LDS(gB0 + k0, lB0);
        GLD_LDS(gB1 + k0, lB1);
        __syncthreads();
        bf16x8 af[8], bfr[4];
        #pragma unroll
        for (int mt = 0; mt < 8; mt++)
            af[mt] = *(const bf16x8*)(As + (wm + mt * 16 + lr) * 32 + quad * 8);
        #pragma unroll
        for (int nt = 0; nt < 4; nt++)
            bfr[nt] = *(const bf16x8*)(Bs + (wn + nt * 16 + lr) * 32 + quad * 8);
        #pragma unroll
        for (int mt = 0; mt < 8; mt++)
            #pragma unroll
            for (int nt = 0; nt < 4; nt++)
                acc[mt][nt] = __builtin_amdgcn_mfma_f32_16x16x32_bf16(
                    af[mt], bfr[nt], acc[mt][nt], 0, 0, 0);
    }

    // epilogue: C/D layout col = lane&15, row = quad*4 + reg
    float* Cs = Cm + (size_t)blockIdx.z * NPAD * NPAD;
    #pragma unroll
    for (int mt = 0; mt < 8; mt++) {
        #pragma unroll
        for (int nt = 0; nt < 4; nt++) {
            const int col = n0 + wn + nt * 16 + lr;
            const int rb  = m0 + wm + mt * 16 + quad * 4;
            #pragma unroll
            for (int r = 0; r < 4; r++)
                Cs[(size_t)(rb + r) * NPAD + col] = acc[mt][nt][r];
        }
    }
}

// ---------------------------------------------------------------------------
// Kernel 4: reduce split-K slabs + bias + relu, then FC2. One block per row.
__global__ __launch_bounds__(256) void fc2_kernel(
    const float* __restrict__ h1, const float* __restrict__ b1,
    const float* __restrict__ w2, const float* __restrict__ b2,
    float* __restrict__ out, int nslab)
{
    const int b = blockIdx.x;
    const int tid = threadIdx.x;
    float acc[NCLS];
    #pragma unroll
    for (int o = 0; o < NCLS; o++) acc[o] = 0.f;
    for (int n = tid; n < NFC1; n += 256) {
        float hv = b1[n];
        for (int s = 0; s < nslab; s++)
            hv += h1[(size_t)s * NPAD * NPAD + (size_t)b * NPAD + n];
        float h = fmaxf(hv, 0.f);
        #pragma unroll
        for (int o = 0; o < NCLS; o++)
            acc[o] = fmaf(h, w2[o * NFC1 + n], acc[o]);
    }
    __shared__ float red[4][NCLS];
    #pragma unroll
    for (int o = 0; o < NCLS; o++) {
        float v = acc[o];
        #pragma unroll
        for (int s = 32; s > 0; s >>= 1) v += __shfl_down(v, s);
        if ((tid & 63) == 0) red[tid >> 6][o] = v;
    }
    __syncthreads();
    if (tid < NCLS)
        out[b * NCLS + tid] = red[0][tid] + red[1][tid] + red[2][tid] +
                              red[3][tid] + b2[tid];
}

// ---------------------------------------------------------------------------
extern "C" void kernel_launch(void* const* d_in, const int* in_sizes, int n_in,
                              void* d_out, int out_size, void* d_ws, size_t ws_size,
                              hipStream_t stream)
{
    (void)n_in; (void)out_size;
    const float* x     = (const float*)d_in[0];
    const float* w_hs  = (const float*)d_in[1];
    const float* b_hs  = (const float*)d_in[2];
    const float* w_ls  = (const float*)d_in[3];
    const float* b_ls  = (const float*)d_in[4];
    const float* w_hi1 = (const float*)d_in[5];
    const float* b_hi1 = (const float*)d_in[6];
    const float* w_hi2 = (const float*)d_in[7];
    const float* b_hi2 = (const float*)d_in[8];
    const float* w_li1 = (const float*)d_in[9];
    const float* b_li1 = (const float*)d_in[10];
    const float* w_li2 = (const float*)d_in[11];
    const float* b_li2 = (const float*)d_in[12];
    const float* w_fc1 = (const float*)d_in[13];
    const float* b_fc1 = (const float*)d_in[14];
    const float* w_fc2 = (const float*)d_in[15];
    const float* b_fc2 = (const float*)d_in[16];
    float* out = (float*)d_out;

    const int B = in_sizes[0] / (T_LEN * C_CH);    // 2048

    char* ws = (char*)d_ws;
    const size_t featB = (size_t)B * KPAD * 2;         // 29.4 MB
    const size_t wbB   = (size_t)NPAD * KPAD * 2;      // 29.4 MB
    const size_t slabB = (size_t)NPAD * NPAD * 4;      // 16.8 MB
    const size_t xtB   = (size_t)T_LEN * C_CH * B * 4; // 51.9 MB
    const size_t base2 = featB + wbB;

    __hip_bfloat16* feat = (__hip_bfloat16*)ws;
    __hip_bfloat16* wb   = (__hip_bfloat16*)(ws + featB);
    float* h1            = (float*)(ws + base2);

    const int sk = (ws_size >= base2 + 4 * slabB) ? 4 : 2;
    const bool use_xt = (ws_size >= base2 + sk * slabB + xtB);
    float* xT = (float*)(ws + base2 + sk * slabB);

    pad_w_kernel<<<dim3((NPAD * 896) / 256), 256, 0, stream>>>(w_fc1, wb);

    const float* cx = x;
    int ts = C_CH, bsi = T_LEN * C_CH, cs = 1;
    if (use_xt) {
        transpose_kernel<<<dim3(99, B / 64), 256, 0, stream>>>(x, xT, B);
        cx = xT; ts = C_CH * B; bsi = 1; cs = B;
    }
    conv_fused_kernel<<<dim3(B / 64, C_CH, 2), 64, 0, stream>>>(
        cx, ts, bsi, cs, w_hs, b_hs, w_ls, b_ls,
        w_hi1, b_hi1, w_hi2, b_hi2, w_li1, b_li1, w_li2, b_li2, feat);
    gemm_kernel<<<dim3(NPAD / 256, B / 256, sk), 512, 0, stream>>>(
        feat, wb, h1, KPAD / sk);
    fc2_kernel<<<dim3(B), 256, 0, stream>>>(h1, b_fc1, w_fc2, b_fc2, out, sk);
}

// Round 6
// 415.325 us; speedup vs baseline: 1.1728x; 1.0597x over previous
//
#include <hip/hip_runtime.h>
#include <hip/hip_bf16.h>

#define T_LEN 96
#define C_CH  66
#define FIN   7128   // 9*66*12
#define KPAD  7168   // 224*32
#define NFC1  1936
#define NPAD  2048
#define NCLS  14

typedef __bf16 bf16x8 __attribute__((ext_vector_type(8)));
typedef float  f32x4  __attribute__((ext_vector_type(4)));

#define GLD_LDS(gp, lp) __builtin_amdgcn_global_load_lds(                     \
    (__attribute__((address_space(1))) void*)(gp),                            \
    (__attribute__((address_space(3))) void*)(lp), 16, 0, 0)

// ---------------------------------------------------------------------------
// Kernel 0: transpose x (B, T*C) -> xT (T*C, B) so conv lanes (lane=b) read
// coalesced. 64x64 LDS tile, +1 pad.
__global__ __launch_bounds__(256) void transpose_kernel(
    const float* __restrict__ x, float* __restrict__ xT, int B)
{
    __shared__ float tile[64][65];
    const int t = threadIdx.x & 63;
    const int w = threadIdx.x >> 6;
    const int tc0 = blockIdx.x * 64;     // 6336 / 64 = 99
    const int b0  = blockIdx.y * 64;     // B / 64
    #pragma unroll
    for (int j = 0; j < 16; j++) {
        const int r = w * 16 + j;
        tile[r][t] = x[(size_t)(b0 + r) * (T_LEN * C_CH) + tc0 + t];
    }
    __syncthreads();
    #pragma unroll
    for (int j = 0; j < 16; j++) {
        const int r = w * 16 + j;
        xT[(size_t)(tc0 + r) * B + b0 + t] = tile[t][r];
    }
}

// ---------------------------------------------------------------------------
// Kernel 1: w_fc1 (1936 x 7128 fp32) -> bf16 (2048 x 7168), zero padded.
__global__ __launch_bounds__(256) void pad_w_kernel(
    const float* __restrict__ w, __hip_bfloat16* __restrict__ wb)
{
    int idx = blockIdx.x * 256 + threadIdx.x;     // chunk id, total 2048*896
    int row = idx / 896;
    int cc  = idx - row * 896;                    // 896 chunks of 8 per row
    float4 a = {0.f, 0.f, 0.f, 0.f}, b = {0.f, 0.f, 0.f, 0.f};
    if (row < NFC1 && cc < 891) {                 // 891*8 = 7128
        const float4* src = (const float4*)(w + (size_t)row * FIN + cc * 8);
        a = src[0];
        b = src[1];
    }
    __align__(16) __hip_bfloat16 v[8];
    v[0] = __float2bfloat16(a.x); v[1] = __float2bfloat16(a.y);
    v[2] = __float2bfloat16(a.z); v[3] = __float2bfloat16(a.w);
    v[4] = __float2bfloat16(b.x); v[5] = __float2bfloat16(b.y);
    v[6] = __float2bfloat16(b.z); v[7] = __float2bfloat16(b.w);
    *(int4*)(wb + (size_t)row * KPAD + cc * 8) = *(const int4*)v;
}

// ---------------------------------------------------------------------------
// Kernel 2: conv branches — EXACT round-0 version (175us, VGPR=128, known
// good; retile attempts demoted arrays to scratch and lost). Per-lane
// pipeline tiled over positions; stage-2 pooled output in s2phR[4][24].
// One lane = one (b, c); grid (B/64, C, 2): z=0 high (K=7), z=1 low (K=3).
template <int K, bool DO_EXTRA>
__device__ __forceinline__ void conv_branch(
    const float* __restrict__ xb, int ts,
    const float* __restrict__ wS, const float* __restrict__ bS,
    const float* __restrict__ wi1, const float* __restrict__ bi1,
    const float* __restrict__ wi2, const float* __restrict__ bi2,
    __hip_bfloat16* __restrict__ frow, int out_off)
{
    constexpr int PAD = K / 2;
    constexpr int XW  = 24 + 6 * PAD;   // x window per tile
    constexpr int THW = 12 + 2 * PAD;   // stage-1 pooled window per tile

    float s2phR[4][24];                 // stage-2 pooled (static indices)

    #pragma unroll
    for (int tt = 0; tt < 4; tt++) {    // fully unrolled: all indices const
        // x window: global t = 24*tt - 3*PAD + i (zero outside [0,96))
        float xw[XW];
        #pragma unroll
        for (int i = 0; i < XW; i++) {
            const int t = 24 * tt - 3 * PAD + i;     // compile-time
            xw[i] = (t >= 0 && t < T_LEN) ? xb[(size_t)t * ts] : 0.f;
        }

        if (DO_EXTRA) {                 // orig = pool2^3: 3 outputs per tile
            #pragma unroll
            for (int r = 0; r < 3; r++) {
                float s = 0.f;
                #pragma unroll
                for (int k = 0; k < 8; k++) s += xw[3 * PAD + 8 * r + k];
                frow[3 * tt + r] = __float2bfloat16(s * 0.125f);
            }
        }

        float s2a[4][12];
        #pragma unroll
        for (int oc = 0; oc < 4; oc++) {
            const float bv = bi1[oc];
            #pragma unroll
            for (int q = 0; q < 12; q++) s2a[oc][q] = bv;
        }

        #pragma unroll 1
        for (int ic = 0; ic < 8; ic++) {
            const float bs1 = bS[ic];
            float thw[THW];             // stage-1 pooled window (this ic)
            #pragma unroll
            for (int j = 0; j < THW; j++) {
                const int jg = 12 * tt - PAD + j;    // compile-time
                if (jg < 0 || jg >= 48) { thw[j] = 0.f; continue; }
                float y0 = bs1, y1 = bs1;
                #pragma unroll
                for (int k = 0; k < K; k++) {
                    const float w = wS[ic * K + k];
                    y0 = fmaf(w, xw[2 * j + k], y0);
                    y1 = fmaf(w, xw[2 * j + 1 + k], y1);
                }
                thw[j] = 0.5f * (fmaxf(y0, 0.f) + fmaxf(y1, 0.f));
            }
            #pragma unroll
            for (int q = 0; q < 12; q++) {
                #pragma unroll
                for (int oc = 0; oc < 4; oc++) {
                    float a = s2a[oc][q];
                    #pragma unroll
                    for (int k = 0; k < K; k++)
                        a = fmaf(wi1[(oc * 8 + ic) * K + k], thw[q + k], a);
                    s2a[oc][q] = a;
                }
            }
        }

        // pool stage 2 -> s2phR[oc][6*tt + r]
        #pragma unroll
        for (int oc = 0; oc < 4; oc++)
            #pragma unroll
            for (int r = 0; r < 6; r++)
                s2phR[oc][6 * tt + r] =
                    0.5f * (fmaxf(s2a[oc][2 * r], 0.f) +
                            fmaxf(s2a[oc][2 * r + 1], 0.f));
    }

    // stage 3 (grouped 4->4) + relu + pool2; OOB taps statically dropped
    #pragma unroll 1
    for (int oc = 0; oc < 4; oc++) {
        const float bv = bi2[oc];
        #pragma unroll
        for (int q = 0; q < 12; q++) {
            float y0 = bv, y1 = bv;
            #pragma unroll
            for (int ic = 0; ic < 4; ic++) {
                #pragma unroll
                for (int k = 0; k < K; k++) {
                    const float w = wi2[(oc * 4 + ic) * K + k];
                    const int i0 = 2 * q + k - PAD;       // compile-time
                    const int i1 = 2 * q + 1 + k - PAD;
                    if (i0 >= 0 && i0 < 24) y0 = fmaf(w, s2phR[ic][i0], y0);
                    if (i1 >= 0 && i1 < 24) y1 = fmaf(w, s2phR[ic][i1], y1);
                }
            }
            frow[out_off + oc * 12 + q] =
                __float2bfloat16(0.5f * (fmaxf(y0, 0.f) + fmaxf(y1, 0.f)));
        }
    }
}

__global__ __launch_bounds__(64, 2) void conv_fused_kernel(
    const float* __restrict__ x, int ts, int bs, int cs,
    const float* __restrict__ w_hs, const float* __restrict__ b_hs,
    const float* __restrict__ w_ls, const float* __restrict__ b_ls,
    const float* __restrict__ w_hi1, const float* __restrict__ b_hi1,
    const float* __restrict__ w_hi2, const float* __restrict__ b_hi2,
    const float* __restrict__ w_li1, const float* __restrict__ b_li1,
    const float* __restrict__ w_li2, const float* __restrict__ b_li2,
    __hip_bfloat16* __restrict__ feat)
{
    const int lane = threadIdx.x;
    const int b = blockIdx.x * 64 + lane;
    const int c = blockIdx.y;
    const float* xb = x + (size_t)b * bs + (size_t)c * cs;
    __hip_bfloat16* frow = feat + (size_t)b * KPAD + c * 108;

    if (blockIdx.z == 0) {
        conv_branch<7, false>(xb, ts, w_hs, b_hs,
                              w_hi1 + c * 224, b_hi1 + c * 4,
                              w_hi2 + c * 112, b_hi2 + c * 4, frow, 60);
    } else {
        if (c == 0) {                   // zero K-pad tail once per row
            int4* tail = (int4*)(feat + (size_t)b * KPAD + FIN);
            const int4 z = {0, 0, 0, 0};
            #pragma unroll
            for (int i = 0; i < 5; i++) tail[i] = z;
        }
        conv_branch<3, true>(xb, ts, w_ls, b_ls,
                             w_li1 + c * 96, b_li1 + c * 4,
                             w_li2 + c * 48, b_li2 + c * 4, frow, 12);
    }
}

// ---------------------------------------------------------------------------
// Kernel 3: FC1 GEMM, A(2048xKPAD bf16) * W(2048xKPAD bf16)^T, split-K.
// ROUND-6: 256x256 tile, BK=64, DOUBLE-BUFFERED LDS with prefetch-before-
// compute (guide T3-minimum 2-phase). The previous structure (sync ->
// GLD_LDS -> sync -> compute) exposed full L3/HBM latency every K-step
// (~280 TF implied). Here the t+1 half-tile loads are issued BEFORE
// computing tile t; the single __syncthreads() per step (implicit
// vmcnt(0)+lgkmcnt(0) drain) lands after ~64 MFMA (~2000cy) have covered
// the latency. Race audit: iter t ds_reads buf[t&1] while GLD writes
// buf[t^1]; the end-of-t barrier guarantees next buffer fully written AND
// all reads of the current buffer done before overwrite at t+1.
// No LDS swizzle: T2 is measured-null at 2-phase (regime gate).
// LDS 128 KiB -> 1 block/CU; 512 thr, 8 waves (2Mx4N), acc[8][4] f32x4.
__global__ __launch_bounds__(512, 2) void gemm_kernel(
    const __hip_bfloat16* __restrict__ A,
    const __hip_bfloat16* __restrict__ Bw,
    float* __restrict__ Cm, int kchunk)
{
    __shared__ __align__(16) __hip_bfloat16 lds[2][2][256 * 64];  // 128 KiB

    const int tid  = threadIdx.x;
    const int lane = tid & 63;
    const int wid  = tid >> 6;          // 0..7
    const int m0 = blockIdx.y * 256;
    const int n0 = blockIdx.x * 256;
    const int wm = (wid >> 2) * 128;    // 2 wave-rows (128 each)
    const int wn = (wid & 3) * 64;      // 4 wave-cols (64 each)
    const int lr = lane & 15;
    const int quad = lane >> 4;

    // staging: thread stages 16B chunks p = tid + 512*r (r=0..3) per half:
    // row = p>>3 (srow + 64r), colchunk = p&7. LDS elem p*8 is linear:
    // GLD dest = wave-uniform (r*4096 + wid*512) + lane*16B.  Legal.
    const int srow = tid >> 3, scol = (tid & 7) * 8;
    const __hip_bfloat16* gA = A  + (size_t)(m0 + srow) * KPAD + scol;
    const __hip_bfloat16* gB = Bw + (size_t)(n0 + srow) * KPAD + scol;

    f32x4 acc[8][4] = {};

    const int kBeg = blockIdx.z * kchunk;
    const int numt = kchunk >> 6;       // K-steps of 64

    // prologue: stage buffer 0
    #pragma unroll
    for (int r = 0; r < 4; r++) {
        GLD_LDS(gA + (size_t)r * 64 * KPAD + kBeg,
                &lds[0][0][r * 4096 + wid * 512]);
        GLD_LDS(gB + (size_t)r * 64 * KPAD + kBeg,
                &lds[0][1][r * 4096 + wid * 512]);
    }
    __syncthreads();

    for (int t = 0; t < numt; ++t) {
        const int cb = t & 1;
        if (t + 1 < numt) {             // issue NEXT tile before computing
            const int k1 = kBeg + (t + 1) * 64;
            #pragma unroll
            for (int r = 0; r < 4; r++) {
                GLD_LDS(gA + (size_t)r * 64 * KPAD + k1,
                        &lds[cb ^ 1][0][r * 4096 + wid * 512]);
                GLD_LDS(gB + (size_t)r * 64 * KPAD + k1,
                        &lds[cb ^ 1][1][r * 4096 + wid * 512]);
            }
        }
        const __hip_bfloat16* As_ = &lds[cb][0][0];
        const __hip_bfloat16* Bs_ = &lds[cb][1][0];
        #pragma unroll
        for (int ks = 0; ks < 2; ks++) {        // k ascending (matches ref)
            bf16x8 bfr[4];
            #pragma unroll
            for (int nn = 0; nn < 4; nn++)
                bfr[nn] = *(const bf16x8*)(Bs_ + ((wn + nn * 16 + lr) << 6) +
                                           ks * 32 + quad * 8);
            #pragma unroll
            for (int mt = 0; mt < 8; mt++) {
                const bf16x8 af = *(const bf16x8*)(As_ +
                        ((wm + mt * 16 + lr) << 6) + ks * 32 + quad * 8);
                #pragma unroll
                for (int nn = 0; nn < 4; nn++)
                    acc[mt][nn] = __builtin_amdgcn_mfma_f32_16x16x32_bf16(
                        af, bfr[nn], acc[mt][nn], 0, 0, 0);
            }
        }
        __syncthreads();                // drains vm+lgkm: buf[cb^1] ready,
    }                                   // buf[cb] reads complete

    // epilogue: C/D layout col = lane&15, row = quad*4 + reg
    float* Cs = Cm + (size_t)blockIdx.z * NPAD * NPAD;
    #pragma unroll
    for (int mt = 0; mt < 8; mt++) {
        #pragma unroll
        for (int nn = 0; nn < 4; nn++) {
            const int col = n0 + wn + nn * 16 + lr;
            const int rb  = m0 + wm + mt * 16 + quad * 4;
            #pragma unroll
            for (int r = 0; r < 4; r++)
                Cs[(size_t)(rb + r) * NPAD + col] = acc[mt][nn][r];
        }
    }
}

// ---------------------------------------------------------------------------
// Kernel 4: reduce split-K slabs + bias + relu, then FC2. One block per row.
__global__ __launch_bounds__(256) void fc2_kernel(
    const float* __restrict__ h1, const float* __restrict__ b1,
    const float* __restrict__ w2, const float* __restrict__ b2,
    float* __restrict__ out, int nslab)
{
    const int b = blockIdx.x;
    const int tid = threadIdx.x;
    float acc[NCLS];
    #pragma unroll
    for (int o = 0; o < NCLS; o++) acc[o] = 0.f;
    for (int n = tid; n < NFC1; n += 256) {
        float hv = b1[n];
        for (int s = 0; s < nslab; s++)
            hv += h1[(size_t)s * NPAD * NPAD + (size_t)b * NPAD + n];
        float h = fmaxf(hv, 0.f);
        #pragma unroll
        for (int o = 0; o < NCLS; o++)
            acc[o] = fmaf(h, w2[o * NFC1 + n], acc[o]);
    }
    __shared__ float red[4][NCLS];
    #pragma unroll
    for (int o = 0; o < NCLS; o++) {
        float v = acc[o];
        #pragma unroll
        for (int s = 32; s > 0; s >>= 1) v += __shfl_down(v, s);
        if ((tid & 63) == 0) red[tid >> 6][o] = v;
    }
    __syncthreads();
    if (tid < NCLS)
        out[b * NCLS + tid] = red[0][tid] + red[1][tid] + red[2][tid] +
                              red[3][tid] + b2[tid];
}

// ---------------------------------------------------------------------------
extern "C" void kernel_launch(void* const* d_in, const int* in_sizes, int n_in,
                              void* d_out, int out_size, void* d_ws, size_t ws_size,
                              hipStream_t stream)
{
    (void)n_in; (void)out_size;
    const float* x     = (const float*)d_in[0];
    const float* w_hs  = (const float*)d_in[1];
    const float* b_hs  = (const float*)d_in[2];
    const float* w_ls  = (const float*)d_in[3];
    const float* b_ls  = (const float*)d_in[4];
    const float* w_hi1 = (const float*)d_in[5];
    const float* b_hi1 = (const float*)d_in[6];
    const float* w_hi2 = (const float*)d_in[7];
    const float* b_hi2 = (const float*)d_in[8];
    const float* w_li1 = (const float*)d_in[9];
    const float* b_li1 = (const float*)d_in[10];
    const float* w_li2 = (const float*)d_in[11];
    const float* b_li2 = (const float*)d_in[12];
    const float* w_fc1 = (const float*)d_in[13];
    const float* b_fc1 = (const float*)d_in[14];
    const float* w_fc2 = (const float*)d_in[15];
    const float* b_fc2 = (const float*)d_in[16];
    float* out = (float*)d_out;

    const int B = in_sizes[0] / (T_LEN * C_CH);    // 2048

    char* ws = (char*)d_ws;
    const size_t featB = (size_t)B * KPAD * 2;         // 29.4 MB
    const size_t wbB   = (size_t)NPAD * KPAD * 2;      // 29.4 MB
    const size_t slabB = (size_t)NPAD * NPAD * 4;      // 16.8 MB
    const size_t xtB   = (size_t)T_LEN * C_CH * B * 4; // 51.9 MB
    const size_t base2 = featB + wbB;

    __hip_bfloat16* feat = (__hip_bfloat16*)ws;
    __hip_bfloat16* wb   = (__hip_bfloat16*)(ws + featB);
    float* h1            = (float*)(ws + base2);

    const int sk = (ws_size >= base2 + 4 * slabB) ? 4 : 2;
    const bool use_xt = (ws_size >= base2 + sk * slabB + xtB);
    float* xT = (float*)(ws + base2 + sk * slabB);

    pad_w_kernel<<<dim3((NPAD * 896) / 256), 256, 0, stream>>>(w_fc1, wb);

    const float* cx = x;
    int ts = C_CH, bsi = T_LEN * C_CH, cs = 1;
    if (use_xt) {
        transpose_kernel<<<dim3(99, B / 64), 256, 0, stream>>>(x, xT, B);
        cx = xT; ts = C_CH * B; bsi = 1; cs = B;
    }
    conv_fused_kernel<<<dim3(B / 64, C_CH, 2), 64, 0, stream>>>(
        cx, ts, bsi, cs, w_hs, b_hs, w_ls, b_ls,
        w_hi1, b_hi1, w_hi2, b_hi2, w_li1, b_li1, w_li2, b_li2, feat);
    gemm_kernel<<<dim3(NPAD / 256, B / 256, sk), 512, 0, stream>>>(
        feat, wb, h1, KPAD / sk);
    fc2_kernel<<<dim3(B), 256, 0, stream>>>(h1, b_fc1, w_fc2, b_fc2, out, sk);
}